// Round 11
// baseline (373.195 us; speedup 1.0000x reference)
//
#include <hip/hip_runtime.h>
#include <cstdint>
#include <math.h>

// Problem constants
#define Bsz 4
#define Lsz 1024
#define Dsz 256
#define Hsz 8
#define HD  2048          // H*D
#define NROWS (Bsz*Lsz)   // 4096
#define INV_TEMP 0.0625f  // 1/sqrt(256)

typedef __attribute__((ext_vector_type(8))) short bf16x8;
typedef __attribute__((ext_vector_type(4))) float f32x4;

__device__ inline unsigned short f2bf(float f) {
    union { float f; unsigned u; } x; x.f = f;
    unsigned r = x.u + 0x7fffu + ((x.u >> 16) & 1u);
    return (unsigned short)(r >> 16);
}
__device__ inline float bf2f(unsigned short u) {
    union { unsigned u; float f; } x; x.u = (unsigned)u << 16; return x.f;
}

#define GBL(p) ((const __attribute__((address_space(1))) unsigned int*)(p))
#define LDS(p) ((__attribute__((address_space(3))) unsigned int*)(p))

template<int N> __device__ __forceinline__ void vmw() {
    if constexpr (N == 0)       asm volatile("s_waitcnt vmcnt(0)"  ::: "memory");
    else if constexpr (N == 3)  asm volatile("s_waitcnt vmcnt(3)"  ::: "memory");
    else if constexpr (N == 6)  asm volatile("s_waitcnt vmcnt(6)"  ::: "memory");
    else if constexpr (N == 10) asm volatile("s_waitcnt vmcnt(10)" ::: "memory");
    else if constexpr (N == 19) asm volatile("s_waitcnt vmcnt(19)" ::: "memory");
    else static_assert(N == 0, "unsupported vmcnt literal");
}

// ============================================================================
// gemm_bt: C = alpha * A @ B^T (used for proj+vt and fc). BK=64, XOR-swizzled
// staging, counted-vmcnt dbuf, LDS round-trip vectorized epilogue (round 10).
// Only EPI=0 instantiated now (scores/pv replaced by attn_fused below).
// ============================================================================
template <int TMv, int TNv, typename OutT, int EPI, int MINW, bool FUSE,
          int GX, int GY, int GZ>
__global__ __launch_bounds__(256, MINW) void gemm_bt(
    const unsigned short* __restrict__ A, const unsigned short* __restrict__ Bm,
    OutT* __restrict__ C,
    int K, int lda, int ldb, int ldc, int inner,
    long long sA1, long long sA2, long long sB1, long long sB2,
    long long sC1, long long sC2, float alpha,
    const unsigned short* __restrict__ A2, const unsigned short* __restrict__ B2,
    unsigned short* __restrict__ C2)
{
    constexpr int WMv = TMv / 2, WNv = TNv / 2;
    constexpr int IT = TMv / 32, JT = TNv / 32;
    constexpr int APASS = TMv / 32, NPASS = (TMv + TNv) / 32;
    constexpr int TILE = (TMv + TNv) * 64;
    constexpr int G = GX * GY * GZ;
    static_assert(G % 8 == 0, "bijective XCD swizzle needs G%8==0");
    static_assert(NPASS == 6, "vmcnt literal assumes NPASS==6");
    static_assert(TMv * (TNv + 4) * 4 <= 2 * TILE * 2, "epilogue LDS overflow");

    const int lid = blockIdx.x + GX * (blockIdx.y + GY * blockIdx.z);
    const int nid = (lid & 7) * (G >> 3) + (lid >> 3);
    int mx = nid % GX;
    const int t1g = nid / GX;
    int my = t1g % GY;
    const int zz = t1g / GY;

    if constexpr (FUSE) {
        if (zz >= 2) {
            const int idx = my * 64 + mx;
            if (idx >= 256) return;
            mx = idx & 31; my = idx >> 5;
            const int b = zz - 2;
            A   = A2;
            Bm  = B2 + (size_t)b * ((size_t)Lsz * Dsz);
            C   = (OutT*)(C2 + (size_t)b * ((size_t)HD * Lsz));
            ldc = Lsz;
        } else {
            A  += (size_t)zz * sA2;
            Bm += (size_t)zz * sB2;
            C  += (size_t)zz * sC2;
        }
    } else {
        const int i1 = zz / inner;
        const int i2 = zz % inner;
        A  += (size_t)i1 * sA1 + (size_t)i2 * sA2;
        Bm += (size_t)i1 * sB1 + (size_t)i2 * sB2;
        C  += (size_t)i1 * sC1 + (size_t)i2 * sC2;
    }

    __shared__ unsigned short S[2 * TILE];

    const int t    = threadIdx.x;
    const int lane = t & 63;
    const int w    = t >> 6;
    const int wm   = w & 1;
    const int wn   = w >> 1;
    const int m0   = mx * TMv;
    const int n0   = my * TNv;

    const int rA = t >> 3;
    const int ch = ((t & 7) ^ (rA & 7)) * 8;
    const unsigned short* gA = A  + (size_t)(m0 + rA) * lda + ch;
    const unsigned short* gB = Bm + (size_t)(n0 + rA) * ldb + ch;

    const int fr = lane & 15;
    const int q  = lane >> 4;

    f32x4 acc[IT][JT];
#pragma unroll
    for (int i = 0; i < IT; ++i)
#pragma unroll
        for (int j = 0; j < JT; ++j) acc[i][j] = (f32x4){0.f, 0.f, 0.f, 0.f};

    auto stage = [&](unsigned short* Sb, int k0) {
#pragma unroll
        for (int p = 0; p < NPASS; ++p) {
            const unsigned short* src = (p < APASS)
                ? (gA + (size_t)p * 32 * lda + k0)
                : (gB + (size_t)(p - APASS) * 32 * ldb + k0);
            __builtin_amdgcn_global_load_lds(GBL(src), LDS(Sb + p * 2048 + t * 8), 16, 0, 0);
        }
    };
    auto kstep = [&](const unsigned short* As) {
        const unsigned short* Bs = As + TMv * 64;
#pragma unroll
        for (int ks = 0; ks < 2; ++ks) {
            const int slot = ((ks * 4 + q) ^ (fr & 7)) * 8;
            bf16x8 a[IT], b[JT];
#pragma unroll
            for (int i = 0; i < IT; ++i)
                a[i] = *(const bf16x8*)(As + (wm * WMv + i * 16 + fr) * 64 + slot);
#pragma unroll
            for (int j = 0; j < JT; ++j)
                b[j] = *(const bf16x8*)(Bs + (wn * WNv + j * 16 + fr) * 64 + slot);
#pragma unroll
            for (int i = 0; i < IT; ++i)
#pragma unroll
                for (int j = 0; j < JT; ++j)
                    acc[i][j] = __builtin_amdgcn_mfma_f32_16x16x32_bf16(a[i], b[j], acc[i][j], 0, 0, 0);
        }
    };

    const int nk = K >> 6;
    stage(S, 0);

    for (int kt = 0; kt < nk; ++kt) {
        if (kt + 1 < nk) stage(S + ((kt + 1) & 1) * TILE, (kt + 1) << 6);
        if (kt + 1 < nk) vmw<6>(); else vmw<0>();
        __builtin_amdgcn_s_barrier();
        kstep(S + (kt & 1) * TILE);
        asm volatile("s_waitcnt lgkmcnt(0)" ::: "memory");
        __builtin_amdgcn_s_barrier();
    }

    // LDS round-trip vectorized epilogue (staging dead past final barrier)
    {
        float* Lf = (float*)S;
        constexpr int LP = TNv + 4;
#pragma unroll
        for (int i = 0; i < IT; ++i)
#pragma unroll
            for (int j = 0; j < JT; ++j) {
                const int col = wn * WNv + j * 16 + fr;
#pragma unroll
                for (int r = 0; r < 4; ++r) {
                    const int row = wm * WMv + i * 16 + q * 4 + r;
                    Lf[row * LP + col] = acc[i][j][r] * alpha;
                }
            }
        __syncthreads();

        constexpr int SEGS = TNv / 32;
        constexpr int RPI  = 256 / SEGS;
#pragma unroll
        for (int it2 = 0; it2 < TMv / RPI; ++it2) {
            const int row = it2 * RPI + t / SEGS;
            const int c0  = (t % SEGS) * 32;
            const float* src = Lf + row * LP + c0;
            if constexpr (sizeof(OutT) == 4) {
                float* dst = (float*)C + (size_t)(m0 + row) * ldc + n0 + c0;
#pragma unroll
                for (int v4 = 0; v4 < 8; ++v4)
                    *(f32x4*)(dst + v4 * 4) = *(const f32x4*)(src + v4 * 4);
            } else {
                unsigned short* dst = (unsigned short*)C + (size_t)(m0 + row) * ldc + n0 + c0;
#pragma unroll
                for (int v8 = 0; v8 < 4; ++v8) {
                    bf16x8 o;
#pragma unroll
                    for (int e = 0; e < 8; ++e) o[e] = (short)f2bf(src[v8 * 8 + e]);
                    *(bf16x8*)(dst + v8 * 8) = o;
                }
            }
        }
    }
}

// ============================================================================
// attn_fused: scores + clamp/mask/exp + rowsum + PV + normalized attn output,
// one kernel. Per wg: 64 q-rows of one (h,b). Q in regs; per 64-key tile:
// QK^T (K tile in LDS) -> exp(clamp) bf16 -> P_lds -> mask (global 16B vec) +
// e-store + local rowsum -> PV accumulate. After loop: inv locally (NO
// atomics), attnv via LDS round trip, fp32 attn from L2-hot e re-read.
// Mask identity: e = m * f2bf(exp(clamp(s))) -- bit-identical to the old
// f2bf(exp(clamp(s)*m)*m) for m in {0,1}.
// ============================================================================
__global__ __launch_bounds__(256, 1) void attn_fused(
    const unsigned short* __restrict__ qh,
    const unsigned short* __restrict__ kh,
    const unsigned short* __restrict__ vt,
    const unsigned char*  __restrict__ maskb,
    unsigned short* __restrict__ e,
    unsigned short* __restrict__ attnv,
    float* __restrict__ attn)
{
    constexpr int G = 16 * 32;
    const int lid = blockIdx.x + 16 * blockIdx.z;
    const int nid = (lid & 7) * (G >> 3) + (lid >> 3);
    const int mx = nid & 15;
    const int z  = nid >> 4;          // z = h*4 + b (head-major, matches attn out)
    const int h = z >> 2, b = z & 3;
    const int m0 = mx * 64;

    const unsigned short* gQ = qh + (size_t)b * Lsz * HD + (size_t)h * Dsz;
    const unsigned short* gK = kh + (size_t)b * Lsz * HD + (size_t)h * Dsz;
    const unsigned short* gV = vt + (size_t)b * HD * Lsz + (size_t)h * Dsz * Lsz;
    const unsigned char*  gM = maskb + (size_t)b * Lsz * Lsz;
    unsigned short* gE = e + (size_t)h * Bsz * Lsz * Lsz + (size_t)b * Lsz * Lsz;
    float* gA = attn + (size_t)z * Lsz * Lsz;

    // LDS: KH dbuf 2x16384 | VT dbuf 2x16384 | P 4096  (ushorts) = 139264 B
    __shared__ unsigned short S[69632];
    __shared__ float rs[64];
    unsigned short* KH = S;
    unsigned short* VT = S + 32768;
    unsigned short* P  = S + 65536;

    const int t = threadIdx.x;
    const int lane = t & 63;
    const int w = t >> 6;
    const int wm = w & 1, wn = w >> 1;
    const int fr = lane & 15, q = lane >> 4;

    if (t < 64) rs[t] = 0.f;

    // Q in registers: A-frags for all 8 d-ksteps (rows wm*32+i*16+fr)
    bf16x8 Qr[2][8];
#pragma unroll
    for (int i = 0; i < 2; ++i) {
        const unsigned short* qrow = gQ + (size_t)(m0 + wm * 32 + i * 16 + fr) * HD;
#pragma unroll
        for (int ks = 0; ks < 8; ++ks)
            Qr[i][ks] = *(const bf16x8*)(qrow + ks * 32 + q * 8);
    }

    // KH tile [64 keys][256 d]: rows 512B = 32 chunks of 16B; swizzle within
    // 8-chunk (128B) groups by row&7 (global-side pre-swizzle, LDS linear).
    auto stageKH = [&](unsigned short* dst, int k0) {
#pragma unroll
        for (int p = 0; p < 8; ++p) {
            const int row = p * 8 + (t >> 5);
            const int c = t & 31;
            const int cs = (c & 24) | ((c & 7) ^ (row & 7));
            const unsigned short* src = gK + (size_t)(k0 + row) * HD + cs * 8;
            __builtin_amdgcn_global_load_lds(GBL(src), LDS(dst + p * 2048 + t * 8), 16, 0, 0);
        }
    };
    // VT tile [256 d][64 keys]: rows 128B = 8 chunks; XOR by row&7.
    auto stageVT = [&](unsigned short* dst, int k0) {
#pragma unroll
        for (int p = 0; p < 8; ++p) {
            const int row = p * 32 + (t >> 3);
            const int cs = (t & 7) ^ (row & 7);
            const unsigned short* src = gV + (size_t)row * Lsz + k0 + cs * 8;
            __builtin_amdgcn_global_load_lds(GBL(src), LDS(dst + p * 2048 + t * 8), 16, 0, 0);
        }
    };

    f32x4 O[2][8];
#pragma unroll
    for (int i = 0; i < 2; ++i)
#pragma unroll
        for (int j = 0; j < 8; ++j) O[i][j] = (f32x4){0.f, 0.f, 0.f, 0.f};

    stageKH(KH, 0); stageVT(VT, 0);
    vmw<0>();
    __syncthreads();   // Q + tile0 + rs-zero all visible

    const int rowB = t >> 2, segB = t & 3;   // step-B ownership: 16 cols/thread

    for (int kt = 0; kt < 16; ++kt) {
        const int cur = kt & 1;
        // mask for THIS tile first (so compiler's wait for it never drains prefetch)
        const unsigned char* mp = gM + (size_t)(m0 + rowB) * Lsz + kt * 64 + segB * 16;
        union { uint4 v; unsigned char c[16]; } mu;
        mu.v = *(const uint4*)mp;
        if (kt + 1 < 16) {
            stageKH(KH + (cur ^ 1) * 16384, (kt + 1) * 64);
            stageVT(VT + (cur ^ 1) * 16384, (kt + 1) * 64);
        }
        // wait tile kt's 16 loads (oldest); newer in queue: prev 2 e-stores,
        // this mask load, 16 prefetch -> N=19. Last iter: only mask+2S newer -> 3.
        if (kt + 1 < 16) vmw<19>(); else vmw<3>();
        __builtin_amdgcn_s_barrier();

        // --- QK^T 64x64 over d=256 ---
        const unsigned short* KHc = KH + cur * 16384;
        f32x4 Sa[2][2];
#pragma unroll
        for (int i = 0; i < 2; ++i)
#pragma unroll
            for (int j = 0; j < 2; ++j) Sa[i][j] = (f32x4){0.f, 0.f, 0.f, 0.f};
#pragma unroll
        for (int ks = 0; ks < 8; ++ks) {
            const int c = ks * 4 + q;
            const int cs = (c & 24) | ((c & 7) ^ (fr & 7));
            bf16x8 bfr[2];
#pragma unroll
            for (int j = 0; j < 2; ++j)
                bfr[j] = *(const bf16x8*)(KHc + (wn * 32 + j * 16 + fr) * 256 + cs * 8);
#pragma unroll
            for (int i = 0; i < 2; ++i)
#pragma unroll
                for (int j = 0; j < 2; ++j)
                    Sa[i][j] = __builtin_amdgcn_mfma_f32_16x16x32_bf16(Qr[i][ks], bfr[j], Sa[i][j], 0, 0, 0);
        }

        // --- step A: f2bf(exp(clamp)) -> P_lds (chunk ^= row&7) ---
#pragma unroll
        for (int i = 0; i < 2; ++i)
#pragma unroll
            for (int r = 0; r < 4; ++r) {
                const int row = wm * 32 + i * 16 + q * 4 + r;
#pragma unroll
                for (int j = 0; j < 2; ++j) {
                    const int col = wn * 32 + j * 16 + fr;
                    float vv = Sa[i][j][r] * INV_TEMP;
                    vv = __expf(fminf(fmaxf(vv, -15.f), 15.f));
                    P[row * 64 + (((col >> 3) ^ (row & 7)) * 8) + (col & 7)] = f2bf(vv);
                }
            }
        asm volatile("s_waitcnt lgkmcnt(0)" ::: "memory");
        __builtin_amdgcn_s_barrier();

        // --- step B: mask-mul, e-store, masked write-back, local rowsum ---
        {
            const int c2a = (segB * 2) ^ (rowB & 7);
            const int c2b = (segB * 2 + 1) ^ (rowB & 7);
            bf16x8 p0 = *(const bf16x8*)(P + rowB * 64 + c2a * 8);
            bf16x8 p1 = *(const bf16x8*)(P + rowB * 64 + c2b * 8);
            float part = 0.f;
#pragma unroll
            for (int e2 = 0; e2 < 8; ++e2) {
                if (!mu.c[e2])     p0[e2] = 0;
                if (!mu.c[8 + e2]) p1[e2] = 0;
                part += bf2f((unsigned short)p0[e2]) + bf2f((unsigned short)p1[e2]);
            }
            unsigned short* ep = gE + (size_t)(m0 + rowB) * Lsz + kt * 64 + segB * 16;
            *(bf16x8*)ep = p0;
            *(bf16x8*)(ep + 8) = p1;
            *(bf16x8*)(P + rowB * 64 + c2a * 8) = p0;
            *(bf16x8*)(P + rowB * 64 + c2b * 8) = p1;
            part += __shfl_xor(part, 1, 64);
            part += __shfl_xor(part, 2, 64);
            if (segB == 0) rs[rowB] += part;   // one thread per row: race-free
        }
        asm volatile("s_waitcnt lgkmcnt(0)" ::: "memory");
        __builtin_amdgcn_s_barrier();

        // --- PV: O += P @ VT^T over 64 keys ---
        const unsigned short* VTc = VT + cur * 16384;
#pragma unroll
        for (int ks2 = 0; ks2 < 2; ++ks2) {
            const int cs = ((ks2 * 4 + q) ^ (fr & 7)) * 8;
            bf16x8 a2[2];
#pragma unroll
            for (int i = 0; i < 2; ++i)
                a2[i] = *(const bf16x8*)(P + (wm * 32 + i * 16 + fr) * 64 + cs);
#pragma unroll
            for (int j = 0; j < 8; ++j) {
                bf16x8 b2 = *(const bf16x8*)(VTc + (wn * 128 + j * 16 + fr) * 64 + cs);
#pragma unroll
                for (int i = 0; i < 2; ++i)
                    O[i][j] = __builtin_amdgcn_mfma_f32_16x16x32_bf16(a2[i], b2, O[i][j], 0, 0, 0);
            }
        }
        asm volatile("s_waitcnt lgkmcnt(0)" ::: "memory");
        __builtin_amdgcn_s_barrier();
    }

    // inv = 1/(rowsum+eps), purely local
    if (t < 64) rs[t] = 1.0f / (rs[t] + 1e-6f);
    __syncthreads();

    // attnv epilogue via LDS round trip (KH/VT/P dead now)
    {
        float* Lf = (float*)S;
#pragma unroll
        for (int i = 0; i < 2; ++i)
#pragma unroll
            for (int j = 0; j < 8; ++j) {
                const int col = wn * 128 + j * 16 + fr;
#pragma unroll
                for (int r = 0; r < 4; ++r)
                    Lf[(wm * 32 + i * 16 + q * 4 + r) * 260 + col] = O[i][j][r];
            }
        __syncthreads();
#pragma unroll
        for (int it2 = 0; it2 < 2; ++it2) {
            const int row = it2 * 32 + (t >> 3);
            const int c0 = (t & 7) * 32;
            const float iv = rs[row];
            const float* src = Lf + row * 260 + c0;
            unsigned short* dst = attnv + ((size_t)b * Lsz + m0 + row) * HD + h * Dsz + c0;
#pragma unroll
            for (int v8 = 0; v8 < 4; ++v8) {
                bf16x8 o;
#pragma unroll
                for (int e2 = 0; e2 < 8; ++e2) o[e2] = (short)f2bf(src[v8 * 8 + e2] * iv);
                *(bf16x8*)(dst + v8 * 8) = o;
            }
        }
    }

    // normalized fp32 attn from own e strip (L2-hot; stores drained first)
    vmw<0>();
    {
        const float iv = rs[rowB];
        const unsigned short* ebase = gE + (size_t)(m0 + rowB) * Lsz + segB * 16;
        float* abase = gA + (size_t)(m0 + rowB) * Lsz + segB * 16;
#pragma unroll 4
        for (int kt = 0; kt < 16; ++kt) {
            const unsigned short* ep = ebase + kt * 64;
            uint4 u0 = *(const uint4*)ep;
            uint4 u1 = *(const uint4*)(ep + 8);
            f32x4 f0, f1, f2, f3;
            f0.x = bf2f((unsigned short)(u0.x & 0xffff)) * iv; f0.y = bf2f((unsigned short)(u0.x >> 16)) * iv;
            f0.z = bf2f((unsigned short)(u0.y & 0xffff)) * iv; f0.w = bf2f((unsigned short)(u0.y >> 16)) * iv;
            f1.x = bf2f((unsigned short)(u0.z & 0xffff)) * iv; f1.y = bf2f((unsigned short)(u0.z >> 16)) * iv;
            f1.z = bf2f((unsigned short)(u0.w & 0xffff)) * iv; f1.w = bf2f((unsigned short)(u0.w >> 16)) * iv;
            f2.x = bf2f((unsigned short)(u1.x & 0xffff)) * iv; f2.y = bf2f((unsigned short)(u1.x >> 16)) * iv;
            f2.z = bf2f((unsigned short)(u1.y & 0xffff)) * iv; f2.w = bf2f((unsigned short)(u1.y >> 16)) * iv;
            f3.x = bf2f((unsigned short)(u1.z & 0xffff)) * iv; f3.y = bf2f((unsigned short)(u1.z >> 16)) * iv;
            f3.z = bf2f((unsigned short)(u1.w & 0xffff)) * iv; f3.w = bf2f((unsigned short)(u1.w >> 16)) * iv;
            float* ap = abase + kt * 64;
            *(f32x4*)ap = f0; *(f32x4*)(ap + 4) = f1;
            *(f32x4*)(ap + 8) = f2; *(f32x4*)(ap + 12) = f3;
        }
    }
}

// ---- fp32->bf16 cast of all GEMM inputs + int32 mask -> BYTE {0,1} ----
__global__ __launch_bounds__(256) void cast_all(
    const float* __restrict__ q, const float* __restrict__ k, const float* __restrict__ v,
    const float* __restrict__ wq, const float* __restrict__ wk, const float* __restrict__ wv,
    const float* __restrict__ fw, const int* __restrict__ mask,
    unsigned short* __restrict__ qb, unsigned short* __restrict__ kb, unsigned short* __restrict__ vb,
    unsigned short* __restrict__ wqb, unsigned short* __restrict__ wkb, unsigned short* __restrict__ wvb,
    unsigned short* __restrict__ fwb, unsigned char* __restrict__ mb)
{
    const int gid = blockIdx.x * 256 + threadIdx.x;
    const int NQ = 262144;   // 1048576/4
    const int NW = 131072;   // 524288/4
    const int NF = 3 * NQ + 4 * NW;   // 1310720 float4 groups
    if (gid >= NF) {
        const int off = gid - NF;     // < 1048576 mask int4 groups
        const int4 mi = ((const int4*)mask)[off];
        uchar4 o;
        o.x = mi.x ? 1 : 0;
        o.y = mi.y ? 1 : 0;
        o.z = mi.z ? 1 : 0;
        o.w = mi.w ? 1 : 0;
        ((uchar4*)mb)[off] = o;
        return;
    }
    const float* src; unsigned short* dst; int off;
    if      (gid < NQ)            { src = q;  dst = qb;  off = gid; }
    else if (gid < 2 * NQ)        { src = k;  dst = kb;  off = gid - NQ; }
    else if (gid < 3 * NQ)        { src = v;  dst = vb;  off = gid - 2 * NQ; }
    else if (gid < 3 * NQ + NW)   { src = wq; dst = wqb; off = gid - 3 * NQ; }
    else if (gid < 3 * NQ + 2*NW) { src = wk; dst = wkb; off = gid - 3 * NQ - NW; }
    else if (gid < 3 * NQ + 3*NW) { src = wv; dst = wvb; off = gid - 3 * NQ - 2 * NW; }
    else                          { src = fw; dst = fwb; off = gid - 3 * NQ - 3 * NW; }
    float4 f = ((const float4*)src)[off];
    ushort4 o;
    o.x = f2bf(f.x); o.y = f2bf(f.y); o.z = f2bf(f.z); o.w = f2bf(f.w);
    ((ushort4*)dst)[off] = o;
}

// ---- sum 4 fc split-K partials + fc_b + residual -> LayerNorm -> out ----
__global__ __launch_bounds__(256) void ln_kernel(const float* __restrict__ gout,
                                                 const float* __restrict__ qin,
                                                 const float* __restrict__ fc_b,
                                                 const float* __restrict__ ln_g,
                                                 const float* __restrict__ ln_b,
                                                 float* __restrict__ out)
{
    const int row = blockIdx.x;
    const int t = threadIdx.x;
    const size_t idx = (size_t)row * Dsz + t;
    const size_t P = (size_t)NROWS * Dsz;
    const float val = gout[idx] + gout[idx + P] + gout[idx + 2 * P] + gout[idx + 3 * P]
                    + fc_b[t] + qin[idx];

    __shared__ float red[4];
    float s = val;
#pragma unroll
    for (int o = 32; o > 0; o >>= 1) s += __shfl_down(s, o, 64);
    const int lane = t & 63, w = t >> 6;
    if (lane == 0) red[w] = s;
    __syncthreads();
    const float mu = (red[0] + red[1] + red[2] + red[3]) * (1.0f / Dsz);
    __syncthreads();

    float d = val - mu;
    float s2 = d * d;
#pragma unroll
    for (int o = 32; o > 0; o >>= 1) s2 += __shfl_down(s2, o, 64);
    if (lane == 0) red[w] = s2;
    __syncthreads();
    const float var = (red[0] + red[1] + red[2] + red[3]) * (1.0f / Dsz);

    out[idx] = d * rsqrtf(var + 1e-5f) * ln_g[t] + ln_b[t];
}

extern "C" void kernel_launch(void* const* d_in, const int* in_sizes, int n_in,
                              void* d_out, int out_size, void* d_ws, size_t ws_size,
                              hipStream_t stream)
{
    const float* q    = (const float*)d_in[0];
    const int*   mask = (const int*)d_in[1];
    const float* k    = (const float*)d_in[2];
    const float* v    = (const float*)d_in[3];
    const float* w_qs = (const float*)d_in[4];
    const float* w_ks = (const float*)d_in[5];
    const float* w_vs = (const float*)d_in[6];
    const float* fc_w = (const float*)d_in[7];
    const float* fc_b = (const float*)d_in[8];
    const float* ln_g = (const float*)d_in[9];
    const float* ln_b = (const float*)d_in[10];

    float* out  = (float*)d_out;                       // [B,L,D]
    float* attn = (float*)d_out + (size_t)NROWS * Dsz; // [H*B,L,L] fp32 normalized

    // Workspace layout (ushort units)
    unsigned short* wsu = (unsigned short*)d_ws;
    unsigned short* qh     = wsu;                                  // [4096,2048]
    unsigned short* kh     = qh + (size_t)NROWS * HD;              // [4096,2048]
    unsigned short* q_bf   = kh + (size_t)NROWS * HD;              // [4096,256] x3
    unsigned short* k_bf   = q_bf + (size_t)NROWS * Dsz;
    unsigned short* v_bf   = k_bf + (size_t)NROWS * Dsz;
    unsigned short* wq_bf  = v_bf + (size_t)NROWS * Dsz;           // [2048,256] x3
    unsigned short* wk_bf  = wq_bf + (size_t)HD * Dsz;
    unsigned short* wv_bf  = wk_bf + (size_t)HD * Dsz;
    unsigned short* vt     = wv_bf + (size_t)HD * Dsz;             // [B,2048,1024]
    unsigned short* attn_e = vt + (size_t)Bsz * HD * Lsz;          // [32,1024,1024] masked e
    unsigned short* attnv  = attn_e + (size_t)32 * Lsz * Lsz;      // [4096,2048]
    unsigned short* fcw_bf = attnv + (size_t)NROWS * HD;           // [256,2048]
    float*          fcout  = (float*)(fcw_bf + (size_t)Dsz * HD);  // [4,4096,256] split-K partials
    unsigned char*  maskb  = (unsigned char*)(fcout + (size_t)4 * NROWS * Dsz); // [B,L,L] bytes

    dim3 blk(256);

    // 0) cast everything to bf16 (mask -> bytes)
    cast_all<<<dim3(9216), blk, 0, stream>>>(q, k, v, w_qs, w_ks, w_vs, fc_w, mask,
                                             q_bf, k_bf, v_bf, wq_bf, wk_bf, wv_bf, fcw_bf, maskb);

    // 1) FUSED proj: q/k (z=0,1) + vt[b] (z=2..5). 64x128, grid 64x16x6, XCD-swizzled.
    {
        dim3 grid(NROWS / 64, HD / 128, 6);
        gemm_bt<64, 128, unsigned short, 0, 3, true, 64, 16, 6><<<grid, blk, 0, stream>>>(
            q_bf, wq_bf, qh,
            Dsz, Dsz, Dsz, HD, 2,
            0, (long long)NROWS * Dsz, 0, (long long)HD * Dsz, 0, (long long)NROWS * HD,
            1.0f,
            wv_bf, v_bf, vt);
    }

    // 2) FUSED attention: scores+softmax+PV+norm in one kernel. grid 16x1x32.
    attn_fused<<<dim3(16, 1, 32), blk, 0, stream>>>(qh, kh, vt, maskb, attn_e, attnv, attn);

    // 3) fc split-K x4: fcout[p] = attnv[:, p*512:+512] @ fc_w[:, p*512:+512]^T.
    //    64x128, grid 64x2x4, XCD-swizzled.
    {
        dim3 grid(NROWS / 64, Dsz / 128, 4);
        gemm_bt<64, 128, float, 0, 3, false, 64, 2, 4><<<grid, blk, 0, stream>>>(
            attnv, fcw_bf, fcout,
            512, HD, HD, Dsz, 4,
            0, 512, 0, 512, 0, (long long)NROWS * Dsz,
            1.0f,
            nullptr, nullptr, nullptr);
    }

    // 4) sum partials + bias + residual + LayerNorm
    ln_kernel<<<dim3(NROWS), blk, 0, stream>>>(fcout, q, fc_b, ln_g, ln_b, out);
}

// Round 12
// 356.944 us; speedup vs baseline: 1.0455x; 1.0455x over previous
//
#include <hip/hip_runtime.h>
#include <cstdint>
#include <math.h>

// Problem constants
#define Bsz 4
#define Lsz 1024
#define Dsz 256
#define Hsz 8
#define HD  2048          // H*D
#define NROWS (Bsz*Lsz)   // 4096
#define INV_TEMP 0.0625f  // 1/sqrt(256)

typedef __attribute__((ext_vector_type(8))) short bf16x8;
typedef __attribute__((ext_vector_type(4))) float f32x4;

__device__ inline unsigned short f2bf(float f) {
    union { float f; unsigned u; } x; x.f = f;
    unsigned r = x.u + 0x7fffu + ((x.u >> 16) & 1u);
    return (unsigned short)(r >> 16);
}
__device__ inline float bf2f(unsigned short u) {
    union { unsigned u; float f; } x; x.u = (unsigned)u << 16; return x.f;
}

#define GBL(p) ((const __attribute__((address_space(1))) unsigned int*)(p))
#define LDS(p) ((__attribute__((address_space(3))) unsigned int*)(p))

template<int N> __device__ __forceinline__ void vmw() {
    if constexpr (N == 0)       asm volatile("s_waitcnt vmcnt(0)"  ::: "memory");
    else if constexpr (N == 1)  asm volatile("s_waitcnt vmcnt(1)"  ::: "memory");
    else if constexpr (N == 6)  asm volatile("s_waitcnt vmcnt(6)"  ::: "memory");
    else if constexpr (N == 10) asm volatile("s_waitcnt vmcnt(10)" ::: "memory");
    else if constexpr (N == 11) asm volatile("s_waitcnt vmcnt(11)" ::: "memory");
    else static_assert(N == 0, "unsupported vmcnt literal");
}

// ============================================================================
// gemm_bt: C = alpha * A @ B^T (proj+vt and fc). BK=64, XOR-swizzled staging,
// counted-vmcnt dbuf, LDS round-trip vectorized epilogue. (round-10 verified)
// ============================================================================
template <int TMv, int TNv, typename OutT, int EPI, int MINW, bool FUSE,
          int GX, int GY, int GZ>
__global__ __launch_bounds__(256, MINW) void gemm_bt(
    const unsigned short* __restrict__ A, const unsigned short* __restrict__ Bm,
    OutT* __restrict__ C,
    int K, int lda, int ldb, int ldc, int inner,
    long long sA1, long long sA2, long long sB1, long long sB2,
    long long sC1, long long sC2, float alpha,
    const unsigned short* __restrict__ A2, const unsigned short* __restrict__ B2,
    unsigned short* __restrict__ C2)
{
    constexpr int WMv = TMv / 2, WNv = TNv / 2;
    constexpr int IT = TMv / 32, JT = TNv / 32;
    constexpr int APASS = TMv / 32, NPASS = (TMv + TNv) / 32;
    constexpr int TILE = (TMv + TNv) * 64;
    constexpr int G = GX * GY * GZ;
    static_assert(G % 8 == 0, "bijective XCD swizzle needs G%8==0");
    static_assert(NPASS == 6, "vmcnt literal assumes NPASS==6");
    static_assert(TMv * (TNv + 4) * 4 <= 2 * TILE * 2, "epilogue LDS overflow");

    const int lid = blockIdx.x + GX * (blockIdx.y + GY * blockIdx.z);
    const int nid = (lid & 7) * (G >> 3) + (lid >> 3);
    int mx = nid % GX;
    const int t1g = nid / GX;
    int my = t1g % GY;
    const int zz = t1g / GY;

    if constexpr (FUSE) {
        if (zz >= 2) {
            const int idx = my * 64 + mx;
            if (idx >= 256) return;
            mx = idx & 31; my = idx >> 5;
            const int b = zz - 2;
            A   = A2;
            Bm  = B2 + (size_t)b * ((size_t)Lsz * Dsz);
            C   = (OutT*)(C2 + (size_t)b * ((size_t)HD * Lsz));
            ldc = Lsz;
        } else {
            A  += (size_t)zz * sA2;
            Bm += (size_t)zz * sB2;
            C  += (size_t)zz * sC2;
        }
    } else {
        const int i1 = zz / inner;
        const int i2 = zz % inner;
        A  += (size_t)i1 * sA1 + (size_t)i2 * sA2;
        Bm += (size_t)i1 * sB1 + (size_t)i2 * sB2;
        C  += (size_t)i1 * sC1 + (size_t)i2 * sC2;
    }

    __shared__ unsigned short S[2 * TILE];

    const int t    = threadIdx.x;
    const int lane = t & 63;
    const int w    = t >> 6;
    const int wm   = w & 1;
    const int wn   = w >> 1;
    const int m0   = mx * TMv;
    const int n0   = my * TNv;

    const int rA = t >> 3;
    const int ch = ((t & 7) ^ (rA & 7)) * 8;
    const unsigned short* gA = A  + (size_t)(m0 + rA) * lda + ch;
    const unsigned short* gB = Bm + (size_t)(n0 + rA) * ldb + ch;

    const int fr = lane & 15;
    const int q  = lane >> 4;

    f32x4 acc[IT][JT];
#pragma unroll
    for (int i = 0; i < IT; ++i)
#pragma unroll
        for (int j = 0; j < JT; ++j) acc[i][j] = (f32x4){0.f, 0.f, 0.f, 0.f};

    auto stage = [&](unsigned short* Sb, int k0) {
#pragma unroll
        for (int p = 0; p < NPASS; ++p) {
            const unsigned short* src = (p < APASS)
                ? (gA + (size_t)p * 32 * lda + k0)
                : (gB + (size_t)(p - APASS) * 32 * ldb + k0);
            __builtin_amdgcn_global_load_lds(GBL(src), LDS(Sb + p * 2048 + t * 8), 16, 0, 0);
        }
    };
    auto kstep = [&](const unsigned short* As) {
        const unsigned short* Bs = As + TMv * 64;
#pragma unroll
        for (int ks = 0; ks < 2; ++ks) {
            const int slot = ((ks * 4 + q) ^ (fr & 7)) * 8;
            bf16x8 a[IT], b[JT];
#pragma unroll
            for (int i = 0; i < IT; ++i)
                a[i] = *(const bf16x8*)(As + (wm * WMv + i * 16 + fr) * 64 + slot);
#pragma unroll
            for (int j = 0; j < JT; ++j)
                b[j] = *(const bf16x8*)(Bs + (wn * WNv + j * 16 + fr) * 64 + slot);
#pragma unroll
            for (int i = 0; i < IT; ++i)
#pragma unroll
                for (int j = 0; j < JT; ++j)
                    acc[i][j] = __builtin_amdgcn_mfma_f32_16x16x32_bf16(a[i], b[j], acc[i][j], 0, 0, 0);
        }
    };

    const int nk = K >> 6;
    stage(S, 0);

    for (int kt = 0; kt < nk; ++kt) {
        if (kt + 1 < nk) stage(S + ((kt + 1) & 1) * TILE, (kt + 1) << 6);
        if (kt + 1 < nk) vmw<6>(); else vmw<0>();
        __builtin_amdgcn_s_barrier();
        kstep(S + (kt & 1) * TILE);
        asm volatile("s_waitcnt lgkmcnt(0)" ::: "memory");
        __builtin_amdgcn_s_barrier();
    }

    // LDS round-trip vectorized epilogue
    {
        float* Lf = (float*)S;
        constexpr int LP = TNv + 4;
#pragma unroll
        for (int i = 0; i < IT; ++i)
#pragma unroll
            for (int j = 0; j < JT; ++j) {
                const int col = wn * WNv + j * 16 + fr;
#pragma unroll
                for (int r = 0; r < 4; ++r) {
                    const int row = wm * WMv + i * 16 + q * 4 + r;
                    Lf[row * LP + col] = acc[i][j][r] * alpha;
                }
            }
        __syncthreads();

        constexpr int SEGS = TNv / 32;
        constexpr int RPI  = 256 / SEGS;
#pragma unroll
        for (int it2 = 0; it2 < TMv / RPI; ++it2) {
            const int row = it2 * RPI + t / SEGS;
            const int c0  = (t % SEGS) * 32;
            const float* src = Lf + row * LP + c0;
            if constexpr (sizeof(OutT) == 4) {
                float* dst = (float*)C + (size_t)(m0 + row) * ldc + n0 + c0;
#pragma unroll
                for (int v4 = 0; v4 < 8; ++v4)
                    *(f32x4*)(dst + v4 * 4) = *(const f32x4*)(src + v4 * 4);
            } else {
                unsigned short* dst = (unsigned short*)C + (size_t)(m0 + row) * ldc + n0 + c0;
#pragma unroll
                for (int v8 = 0; v8 < 4; ++v8) {
                    bf16x8 o;
#pragma unroll
                    for (int e = 0; e < 8; ++e) o[e] = (short)f2bf(src[v8 * 8 + e]);
                    *(bf16x8*)(dst + v8 * 8) = o;
                }
            }
        }
    }
}

// ============================================================================
// attn_fused v2: KVBLK=32, 74 KB LDS -> 2 wg/CU (8 waves). Wave w owns q-rows
// w*16..w*16+16: QK^T, P-write, e-store, PV all touch ONLY that wave's P rows
// -> no cross-wave P dependency -> 2 barriers/tile (stage-ready, buffer-free);
// everything else wave-local lgkmcnt. Mask staged to LDS via global_load_lds.
// Counted vmcnt: 10 ops/tile (4 KH + 4 VT + 2 mask); waits 10 (kt=0), 11
// (steady: +1 for prev e-store), 1 (last). rowsum purely local (no atomics).
// e = m ? f2bf(exp(clamp(s))) : 0  -- bit-identical to reference formula.
// ============================================================================
__global__ __launch_bounds__(256, 2) void attn_fused(
    const unsigned short* __restrict__ qh,
    const unsigned short* __restrict__ kh,
    const unsigned short* __restrict__ vt,
    const unsigned char*  __restrict__ maskb,
    unsigned short* __restrict__ e,
    unsigned short* __restrict__ attnv,
    float* __restrict__ attn)
{
    constexpr int G = 16 * 32;
    const int lid = blockIdx.x + 16 * blockIdx.z;
    const int nid = (lid & 7) * (G >> 3) + (lid >> 3);
    const int mx = nid & 15;
    const int z  = nid >> 4;          // z = h*4 + b (head-major)
    const int h = z >> 2, b = z & 3;
    const int m0 = mx * 64;

    const unsigned short* gQ = qh + (size_t)b * Lsz * HD + (size_t)h * Dsz;
    const unsigned short* gK = kh + (size_t)b * Lsz * HD + (size_t)h * Dsz;
    const unsigned short* gV = vt + (size_t)b * HD * Lsz + (size_t)h * Dsz * Lsz;
    const unsigned char*  gM = maskb + (size_t)b * Lsz * Lsz;
    unsigned short* gE = e + (size_t)z * Lsz * Lsz;
    float* gA = attn + (size_t)z * Lsz * Lsz;

    // LDS (ushorts): KH dbuf [0,16384) | VT dbuf [16384,32768) | P [32768,34816)
    //                mask dbuf [34816,36864)  = 73728 B; rs 256 B.
    __shared__ unsigned short S[36864];
    __shared__ float rs[64];
    unsigned short* P = S + 32768;

    const int t = threadIdx.x;
    const int lane = t & 63;
    const int w = t >> 6;
    const int fr = lane & 15, q = lane >> 4;

    if (t < 64) rs[t] = 0.f;

    // Q in regs: row w*16+fr, all 8 d-ksteps (32 VGPR)
    bf16x8 Qr[8];
    {
        const unsigned short* qrow = gQ + (size_t)(m0 + w * 16 + fr) * HD;
#pragma unroll
        for (int ks = 0; ks < 8; ++ks)
            Qr[ks] = *(const bf16x8*)(qrow + ks * 32 + q * 8);
    }

    // Stage one 32-key tile: KH [32][256] (chunk^row&7 in 128B groups),
    // VT [256][32] (chunk^((row>>1)&3)), mask [64][32] bytes linear.
    auto stageTile = [&](int buf, int kt) {
        unsigned short* KHd = S + buf * 8192;
        unsigned short* VTd = S + 16384 + buf * 8192;
        unsigned char*  Md  = (unsigned char*)(S + 34816) + buf * 2048;
        const int k0 = kt * 32;
#pragma unroll
        for (int p = 0; p < 4; ++p) {
            const int row = p * 8 + (t >> 5);
            const int c = t & 31;
            const int cs = (c & 24) | ((c & 7) ^ (row & 7));
            __builtin_amdgcn_global_load_lds(GBL(gK + (size_t)(k0 + row) * HD + cs * 8),
                                             LDS(KHd + p * 2048 + t * 8), 16, 0, 0);
        }
#pragma unroll
        for (int p = 0; p < 4; ++p) {
            const int row = p * 64 + (t >> 2);
            const int cs = (t & 3) ^ ((t >> 3) & 3);
            __builtin_amdgcn_global_load_lds(GBL(gV + (size_t)row * Lsz + k0 + cs * 8),
                                             LDS(VTd + p * 2048 + t * 8), 16, 0, 0);
        }
#pragma unroll
        for (int p = 0; p < 2; ++p) {
            const int mrow = p * 32 + (t >> 3);
            const int mcol = (t & 7) * 4;
            __builtin_amdgcn_global_load_lds(GBL(gM + (size_t)(m0 + mrow) * Lsz + k0 + mcol),
                                             LDS(Md + p * 1024 + t * 4), 4, 0, 0);
        }
    };

    f32x4 O[16];
#pragma unroll
    for (int j = 0; j < 16; ++j) O[j] = (f32x4){0.f, 0.f, 0.f, 0.f};

    stageTile(0, 0);

    for (int kt = 0; kt < 32; ++kt) {
        const int cur = kt & 1;
        if (kt + 1 < 32) stageTile(cur ^ 1, kt + 1);
        // oldest-first (m135): newer than tile kt's 10 loads = [prev e-store] + 10
        if (kt + 1 < 32) { if (kt >= 1) vmw<11>(); else vmw<10>(); }
        else vmw<1>();
        __builtin_amdgcn_s_barrier();   // B1: tile kt staged

        const unsigned short* KHc = S + cur * 8192;
        const unsigned short* VTc = S + 16384 + cur * 8192;
        const unsigned char*  Mc  = (const unsigned char*)(S + 34816) + cur * 2048;

        // --- QK^T: 16 q-rows (wave-owned) x 32 keys over d=256 ---
        f32x4 Sa[2] = {(f32x4){0.f,0.f,0.f,0.f}, (f32x4){0.f,0.f,0.f,0.f}};
#pragma unroll
        for (int ks = 0; ks < 8; ++ks) {
            const int c = ks * 4 + q;
            const int cs = (c & 24) | ((c & 7) ^ (fr & 7));
#pragma unroll
            for (int j = 0; j < 2; ++j) {
                bf16x8 bfr = *(const bf16x8*)(KHc + (j * 16 + fr) * 256 + cs * 8);
                Sa[j] = __builtin_amdgcn_mfma_f32_16x16x32_bf16(Qr[ks], bfr, Sa[j], 0, 0, 0);
            }
        }

        // --- step A: exp(clamp) + mask (LDS bytes) -> P (chunk ^ (row>>2)&3) ---
#pragma unroll
        for (int j = 0; j < 2; ++j)
#pragma unroll
            for (int r = 0; r < 4; ++r) {
                const int row = w * 16 + q * 4 + r;
                const int col = j * 16 + fr;
                float vv = Sa[j][r] * INV_TEMP;
                vv = __expf(fminf(fmaxf(vv, -15.f), 15.f));
                P[row * 32 + (((j * 2 + (fr >> 3)) ^ q) * 8) + (fr & 7)]
                    = Mc[row * 32 + col] ? f2bf(vv) : (unsigned short)0;
            }
        asm volatile("s_waitcnt lgkmcnt(0)" ::: "memory");  // own wave's P writes done

        // --- step B: e-store + local rowsum (own-wave P rows) ---
        {
            const int rowB = w * 16 + (lane >> 2);
            const int segB = lane & 3;
            const int cch = segB ^ ((lane >> 4) & 3);
            bf16x8 p0 = *(const bf16x8*)(P + rowB * 32 + cch * 8);
            float part = 0.f;
#pragma unroll
            for (int e2 = 0; e2 < 8; ++e2) part += bf2f((unsigned short)p0[e2]);
            *(bf16x8*)(gE + (size_t)(m0 + rowB) * Lsz + kt * 32 + segB * 8) = p0;
            part += __shfl_xor(part, 1, 64);
            part += __shfl_xor(part, 2, 64);
            if (segB == 0) rs[rowB] += part;   // same thread each tile: race-free
        }

        // --- PV: O[16 rows][256 d] += P @ VT^T (32 keys = 1 MFMA k-step) ---
        {
            bf16x8 a2 = *(const bf16x8*)(P + (w * 16 + fr) * 32 + ((q ^ ((fr >> 2) & 3)) * 8));
#pragma unroll
            for (int j = 0; j < 16; ++j) {
                bf16x8 b2 = *(const bf16x8*)(VTc + (j * 16 + fr) * 32 + ((q ^ ((fr >> 1) & 3)) * 8));
                O[j] = __builtin_amdgcn_mfma_f32_16x16x32_bf16(a2, b2, O[j], 0, 0, 0);
            }
        }
        asm volatile("s_waitcnt lgkmcnt(0)" ::: "memory");
        __builtin_amdgcn_s_barrier();   // B2: buf readers done before overwrite
    }

    // inv = 1/(rowsum+eps), purely local
    if (t < 64) rs[t] = 1.0f / (rs[t] + 1e-6f);
    __syncthreads();

    // attnv epilogue via LDS round trip (KH/VT/P dead; rs separate)
    {
        float* Lf = (float*)S;
#pragma unroll
        for (int j = 0; j < 16; ++j)
#pragma unroll
            for (int r = 0; r < 4; ++r)
                Lf[(w * 16 + q * 4 + r) * 260 + j * 16 + fr] = O[j][r];
        __syncthreads();
#pragma unroll
        for (int it2 = 0; it2 < 2; ++it2) {
            const int row = it2 * 32 + (t >> 3);
            const int c0 = (t & 7) * 32;
            const float iv = rs[row];
            const float* src = Lf + row * 260 + c0;
            unsigned short* dst = attnv + ((size_t)b * Lsz + m0 + row) * HD + h * Dsz + c0;
#pragma unroll
            for (int v8 = 0; v8 < 4; ++v8) {
                bf16x8 o;
#pragma unroll
                for (int e2 = 0; e2 < 8; ++e2) o[e2] = (short)f2bf(src[v8 * 8 + e2] * iv);
                *(bf16x8*)(dst + v8 * 8) = o;
            }
        }
    }

    // normalized fp32 attn from own e strip (same-wave stores; drain then read)
    vmw<0>();
    {
        const int rowB = t >> 2;
        const int segB = t & 3;
        const float iv = rs[rowB];
        const unsigned short* ebase = gE + (size_t)(m0 + rowB) * Lsz + segB * 16;
        float* abase = gA + (size_t)(m0 + rowB) * Lsz + segB * 16;
#pragma unroll 4
        for (int kt = 0; kt < 16; ++kt) {
            const unsigned short* ep = ebase + kt * 64;
            uint4 u0 = *(const uint4*)ep;
            uint4 u1 = *(const uint4*)(ep + 8);
            f32x4 f0, f1, f2, f3;
            f0.x = bf2f((unsigned short)(u0.x & 0xffff)) * iv; f0.y = bf2f((unsigned short)(u0.x >> 16)) * iv;
            f0.z = bf2f((unsigned short)(u0.y & 0xffff)) * iv; f0.w = bf2f((unsigned short)(u0.y >> 16)) * iv;
            f1.x = bf2f((unsigned short)(u0.z & 0xffff)) * iv; f1.y = bf2f((unsigned short)(u0.z >> 16)) * iv;
            f1.z = bf2f((unsigned short)(u0.w & 0xffff)) * iv; f1.w = bf2f((unsigned short)(u0.w >> 16)) * iv;
            f2.x = bf2f((unsigned short)(u1.x & 0xffff)) * iv; f2.y = bf2f((unsigned short)(u1.x >> 16)) * iv;
            f2.z = bf2f((unsigned short)(u1.y & 0xffff)) * iv; f2.w = bf2f((unsigned short)(u1.y >> 16)) * iv;
            f3.x = bf2f((unsigned short)(u1.z & 0xffff)) * iv; f3.y = bf2f((unsigned short)(u1.z >> 16)) * iv;
            f3.z = bf2f((unsigned short)(u1.w & 0xffff)) * iv; f3.w = bf2f((unsigned short)(u1.w >> 16)) * iv;
            float* ap = abase + kt * 64;
            *(f32x4*)ap = f0; *(f32x4*)(ap + 4) = f1;
            *(f32x4*)(ap + 8) = f2; *(f32x4*)(ap + 12) = f3;
        }
    }
}

// ---- fp32->bf16 cast of all GEMM inputs + int32 mask -> BYTE {0,1} ----
__global__ __launch_bounds__(256) void cast_all(
    const float* __restrict__ q, const float* __restrict__ k, const float* __restrict__ v,
    const float* __restrict__ wq, const float* __restrict__ wk, const float* __restrict__ wv,
    const float* __restrict__ fw, const int* __restrict__ mask,
    unsigned short* __restrict__ qb, unsigned short* __restrict__ kb, unsigned short* __restrict__ vb,
    unsigned short* __restrict__ wqb, unsigned short* __restrict__ wkb, unsigned short* __restrict__ wvb,
    unsigned short* __restrict__ fwb, unsigned char* __restrict__ mb)
{
    const int gid = blockIdx.x * 256 + threadIdx.x;
    const int NQ = 262144;   // 1048576/4
    const int NW = 131072;   // 524288/4
    const int NF = 3 * NQ + 4 * NW;   // 1310720 float4 groups
    if (gid >= NF) {
        const int off = gid - NF;     // < 1048576 mask int4 groups
        const int4 mi = ((const int4*)mask)[off];
        uchar4 o;
        o.x = mi.x ? 1 : 0;
        o.y = mi.y ? 1 : 0;
        o.z = mi.z ? 1 : 0;
        o.w = mi.w ? 1 : 0;
        ((uchar4*)mb)[off] = o;
        return;
    }
    const float* src; unsigned short* dst; int off;
    if      (gid < NQ)            { src = q;  dst = qb;  off = gid; }
    else if (gid < 2 * NQ)        { src = k;  dst = kb;  off = gid - NQ; }
    else if (gid < 3 * NQ)        { src = v;  dst = vb;  off = gid - 2 * NQ; }
    else if (gid < 3 * NQ + NW)   { src = wq; dst = wqb; off = gid - 3 * NQ; }
    else if (gid < 3 * NQ + 2*NW) { src = wk; dst = wkb; off = gid - 3 * NQ - NW; }
    else if (gid < 3 * NQ + 3*NW) { src = wv; dst = wvb; off = gid - 3 * NQ - 2 * NW; }
    else                          { src = fw; dst = fwb; off = gid - 3 * NQ - 3 * NW; }
    float4 f = ((const float4*)src)[off];
    ushort4 o;
    o.x = f2bf(f.x); o.y = f2bf(f.y); o.z = f2bf(f.z); o.w = f2bf(f.w);
    ((ushort4*)dst)[off] = o;
}

// ---- sum 4 fc split-K partials + fc_b + residual -> LayerNorm -> out ----
__global__ __launch_bounds__(256) void ln_kernel(const float* __restrict__ gout,
                                                 const float* __restrict__ qin,
                                                 const float* __restrict__ fc_b,
                                                 const float* __restrict__ ln_g,
                                                 const float* __restrict__ ln_b,
                                                 float* __restrict__ out)
{
    const int row = blockIdx.x;
    const int t = threadIdx.x;
    const size_t idx = (size_t)row * Dsz + t;
    const size_t P = (size_t)NROWS * Dsz;
    const float val = gout[idx] + gout[idx + P] + gout[idx + 2 * P] + gout[idx + 3 * P]
                    + fc_b[t] + qin[idx];

    __shared__ float red[4];
    float s = val;
#pragma unroll
    for (int o = 32; o > 0; o >>= 1) s += __shfl_down(s, o, 64);
    const int lane = t & 63, w = t >> 6;
    if (lane == 0) red[w] = s;
    __syncthreads();
    const float mu = (red[0] + red[1] + red[2] + red[3]) * (1.0f / Dsz);
    __syncthreads();

    float d = val - mu;
    float s2 = d * d;
#pragma unroll
    for (int o = 32; o > 0; o >>= 1) s2 += __shfl_down(s2, o, 64);
    if (lane == 0) red[w] = s2;
    __syncthreads();
    const float var = (red[0] + red[1] + red[2] + red[3]) * (1.0f / Dsz);

    out[idx] = d * rsqrtf(var + 1e-5f) * ln_g[t] + ln_b[t];
}

extern "C" void kernel_launch(void* const* d_in, const int* in_sizes, int n_in,
                              void* d_out, int out_size, void* d_ws, size_t ws_size,
                              hipStream_t stream)
{
    const float* q    = (const float*)d_in[0];
    const int*   mask = (const int*)d_in[1];
    const float* k    = (const float*)d_in[2];
    const float* v    = (const float*)d_in[3];
    const float* w_qs = (const float*)d_in[4];
    const float* w_ks = (const float*)d_in[5];
    const float* w_vs = (const float*)d_in[6];
    const float* fc_w = (const float*)d_in[7];
    const float* fc_b = (const float*)d_in[8];
    const float* ln_g = (const float*)d_in[9];
    const float* ln_b = (const float*)d_in[10];

    float* out  = (float*)d_out;                       // [B,L,D]
    float* attn = (float*)d_out + (size_t)NROWS * Dsz; // [H*B,L,L] fp32 normalized

    // Workspace layout (ushort units)
    unsigned short* wsu = (unsigned short*)d_ws;
    unsigned short* qh     = wsu;                                  // [4096,2048]
    unsigned short* kh     = qh + (size_t)NROWS * HD;              // [4096,2048]
    unsigned short* q_bf   = kh + (size_t)NROWS * HD;              // [4096,256] x3
    unsigned short* k_bf   = q_bf + (size_t)NROWS * Dsz;
    unsigned short* v_bf   = k_bf + (size_t)NROWS * Dsz;
    unsigned short* wq_bf  = v_bf + (size_t)NROWS * Dsz;           // [2048,256] x3
    unsigned short* wk_bf  = wq_bf + (size_t)HD * Dsz;
    unsigned short* wv_bf  = wk_bf + (size_t)HD * Dsz;
    unsigned short* vt     = wv_bf + (size_t)HD * Dsz;             // [B,2048,1024]
    unsigned short* attn_e = vt + (size_t)Bsz * HD * Lsz;          // [32,1024,1024] masked e
    unsigned short* attnv  = attn_e + (size_t)32 * Lsz * Lsz;      // [4096,2048]
    unsigned short* fcw_bf = attnv + (size_t)NROWS * HD;           // [256,2048]
    float*          fcout  = (float*)(fcw_bf + (size_t)Dsz * HD);  // [4,4096,256] split-K partials
    unsigned char*  maskb  = (unsigned char*)(fcout + (size_t)4 * NROWS * Dsz); // [B,L,L] bytes

    dim3 blk(256);

    // 0) cast everything to bf16 (mask -> bytes)
    cast_all<<<dim3(9216), blk, 0, stream>>>(q, k, v, w_qs, w_ks, w_vs, fc_w, mask,
                                             q_bf, k_bf, v_bf, wq_bf, wk_bf, wv_bf, fcw_bf, maskb);

    // 1) FUSED proj: q/k (z=0,1) + vt[b] (z=2..5). 64x128, grid 64x16x6, XCD-swizzled.
    {
        dim3 grid(NROWS / 64, HD / 128, 6);
        gemm_bt<64, 128, unsigned short, 0, 3, true, 64, 16, 6><<<grid, blk, 0, stream>>>(
            q_bf, wq_bf, qh,
            Dsz, Dsz, Dsz, HD, 2,
            0, (long long)NROWS * Dsz, 0, (long long)HD * Dsz, 0, (long long)NROWS * HD,
            1.0f,
            wv_bf, v_bf, vt);
    }

    // 2) FUSED attention v2: KVBLK=32, 2 wg/CU, 2 barriers/tile. grid 16x1x32.
    attn_fused<<<dim3(16, 1, 32), blk, 0, stream>>>(qh, kh, vt, maskb, attn_e, attnv, attn);

    // 3) fc split-K x4: fcout[p] = attnv[:, p*512:+512] @ fc_w[:, p*512:+512]^T.
    //    64x128, grid 64x2x4, XCD-swizzled.
    {
        dim3 grid(NROWS / 64, Dsz / 128, 4);
        gemm_bt<64, 128, float, 0, 3, false, 64, 2, 4><<<grid, blk, 0, stream>>>(
            attnv, fcw_bf, fcout,
            512, HD, HD, Dsz, 4,
            0, 512, 0, 512, 0, (long long)NROWS * Dsz,
            1.0f,
            nullptr, nullptr, nullptr);
    }

    // 4) sum partials + bias + residual + LayerNorm
    ln_kernel<<<dim3(NROWS), blk, 0, stream>>>(fcout, q, fc_b, ln_g, ln_b, out);
}

// Round 13
// 336.080 us; speedup vs baseline: 1.1104x; 1.0621x over previous
//
#include <hip/hip_runtime.h>
#include <cstdint>
#include <math.h>

// Problem constants
#define Bsz 4
#define Lsz 1024
#define Dsz 256
#define Hsz 8
#define HD  2048          // H*D
#define NROWS (Bsz*Lsz)   // 4096
#define INV_TEMP 0.0625f  // 1/sqrt(256)

typedef __attribute__((ext_vector_type(8))) short bf16x8;
typedef __attribute__((ext_vector_type(4))) float f32x4;

__device__ inline unsigned short f2bf(float f) {
    union { float f; unsigned u; } x; x.f = f;
    unsigned r = x.u + 0x7fffu + ((x.u >> 16) & 1u);
    return (unsigned short)(r >> 16);
}
__device__ inline float bf2f(unsigned short u) {
    union { unsigned u; float f; } x; x.u = (unsigned)u << 16; return x.f;
}

#define GBL(p) ((const __attribute__((address_space(1))) unsigned int*)(p))
#define LDS(p) ((__attribute__((address_space(3))) unsigned int*)(p))

template<int N> __device__ __forceinline__ void vmw() {
    if constexpr (N == 0)       asm volatile("s_waitcnt vmcnt(0)"  ::: "memory");
    else if constexpr (N == 4)  asm volatile("s_waitcnt vmcnt(4)"  ::: "memory");
    else if constexpr (N == 6)  asm volatile("s_waitcnt vmcnt(6)"  ::: "memory");
    else if constexpr (N == 10) asm volatile("s_waitcnt vmcnt(10)" ::: "memory");
    else if constexpr (N == 12) asm volatile("s_waitcnt vmcnt(12)" ::: "memory");
    else if constexpr (N == 14) asm volatile("s_waitcnt vmcnt(14)" ::: "memory");
    else static_assert(N == 0, "unsupported vmcnt literal");
}

// C = alpha * A @ B^T.  A [M,K] bf16 lda; Bm [N,K] bf16 ldb.
// BK=64, XOR-swizzled LDS staging + ds_read_b128 frags; counted-vmcnt pipeline.
// 4 waves as 2x2 quadrants of (TMv/2)x(TNv/2).  XCD-aware bijective wg remap.
//
// Round 13 = round-10 champion + NBUF=3 (depth-2 prefetch) for the short-K
// stages (proj/scores nk=4, fc nk=8): with depth-1 the 4-step pipeline never
// fills -- ~2 of 4 tile latencies fully exposed (the ~2.4 TB/s plateau
// signature seen in every profile). 3 buffers x 24 KB = 72 KB -> 2 wg/CU.
// Waits for NBUF=3: steady vmcnt(12) (2 tiles in flight), then 6, then 0.
// pv (nk=16, 40 KB tiles) stays NBUF=2 with its in-loop attn write.
//
// EPI: 0 = plain store; 1 = scores (clamp*mask, exp*mask, bf16, rowsum
//      atomics; vectorized LDS round-trip epilogue);
//      2 = pv (TNv=256, gridDim.y==1): attnv scaled by inv=1/(rowsum+eps);
//          IN-LOOP: re-read A(e)-tile from LDS, normalize, write fp32 attn.
// FUSE: z<2 = q/k projection; z in [2,6) = vt[b=z-2] = w_vs @ v_b^T remapped.
template <int TMv, int TNv, typename OutT, int EPI, int MINW, bool FUSE,
          int NBUF, int GX, int GY, int GZ>
__global__ __launch_bounds__(256, MINW) void gemm_bt(
    const unsigned short* __restrict__ A, const unsigned short* __restrict__ Bm,
    OutT* __restrict__ C,
    int K, int lda, int ldb, int ldc, int inner,
    long long sA1, long long sA2, long long sB1, long long sB2,
    long long sC1, long long sC2, float alpha,
    const unsigned char* __restrict__ maskb, long long sM2,
    const float* __restrict__ invs, long long sI1, long long sI2,
    float* __restrict__ aux,
    const unsigned short* __restrict__ A2, const unsigned short* __restrict__ B2,
    unsigned short* __restrict__ C2)
{
    constexpr int WMv = TMv / 2, WNv = TNv / 2;
    constexpr int IT = TMv / 32, JT = TNv / 32;
    constexpr int APASS = TMv / 32, NPASS = (TMv + TNv) / 32;
    constexpr int TILE = (TMv + TNv) * 64;   // ushorts per k-tile
    constexpr int G = GX * GY * GZ;
    static_assert(G % 8 == 0, "bijective XCD swizzle needs G%8==0");
    static_assert(NPASS == 6 || NPASS == 10, "vmcnt literals assume NPASS in {6,10}");
    static_assert(NBUF == 2 || NBUF == 3, "NBUF in {2,3}");
    static_assert(NBUF == 2 || NPASS == 6, "NBUF==3 vmcnt literal assumes NPASS==6");
    static_assert(EPI != 2 || NBUF == 2, "EPI==2 in-loop indexing assumes NBUF==2");
    static_assert(EPI != 1 || TNv == 128, "EPI=1 rowsum shfl assumes 4 segs");
    static_assert(TMv * (TNv + 4) * 4 <= NBUF * TILE * 2, "epilogue LDS overflow");

    // ---- XCD-aware bijective remap: each XCD gets a contiguous nid chunk ----
    const int lid = blockIdx.x + GX * (blockIdx.y + GY * blockIdx.z);
    const int nid = (lid & 7) * (G >> 3) + (lid >> 3);
    int mx = nid % GX;
    const int t1g = nid / GX;
    int my = t1g % GY;
    const int zz = t1g / GY;

    if constexpr (FUSE) {
        if (zz >= 2) {
            const int idx = my * 64 + mx;
            if (idx >= 256) return;            // vt slice is 32x8 wg-tiles
            mx = idx & 31; my = idx >> 5;
            const int b = zz - 2;
            A   = A2;
            Bm  = B2 + (size_t)b * ((size_t)Lsz * Dsz);
            C   = (OutT*)(C2 + (size_t)b * ((size_t)HD * Lsz));
            ldc = Lsz;
        } else {
            A  += (size_t)zz * sA2;
            Bm += (size_t)zz * sB2;
            C  += (size_t)zz * sC2;
        }
    } else {
        const int i1 = zz / inner;
        const int i2 = zz % inner;
        A  += (size_t)i1 * sA1 + (size_t)i2 * sA2;
        Bm += (size_t)i1 * sB1 + (size_t)i2 * sB2;
        C  += (size_t)i1 * sC1 + (size_t)i2 * sC2;
        if (EPI == 1) { maskb += (size_t)i2 * sM2; aux += (size_t)zz * Lsz; }
        if (EPI == 2) { invs  += (size_t)i1 * sI1 + (size_t)i2 * sI2; aux += (size_t)zz * Lsz * Lsz; }
    }

    __shared__ unsigned short S[NBUF * TILE];

    const int t    = threadIdx.x;
    const int lane = t & 63;
    const int w    = t >> 6;
    const int wm   = w & 1;
    const int wn   = w >> 1;
    const int m0   = mx * TMv;
    const int n0   = my * TNv;

    // staging: 32 rows per pass, 8 threads/row, 16B each; global chunk XOR-swizzled by row
    const int rA = t >> 3;
    const int ch = ((t & 7) ^ (rA & 7)) * 8;
    const unsigned short* gA = A  + (size_t)(m0 + rA) * lda + ch;
    const unsigned short* gB = Bm + (size_t)(n0 + rA) * ldb + ch;

    const int fr = lane & 15;
    const int q  = lane >> 4;

    f32x4 acc[IT][JT];
#pragma unroll
    for (int i = 0; i < IT; ++i)
#pragma unroll
        for (int j = 0; j < JT; ++j) acc[i][j] = (f32x4){0.f, 0.f, 0.f, 0.f};

    auto stage = [&](unsigned short* Sb, int k0) {
#pragma unroll
        for (int p = 0; p < NPASS; ++p) {
            const unsigned short* src = (p < APASS)
                ? (gA + (size_t)p * 32 * lda + k0)
                : (gB + (size_t)(p - APASS) * 32 * ldb + k0);
            __builtin_amdgcn_global_load_lds(GBL(src), LDS(Sb + p * 2048 + t * 8), 16, 0, 0);
        }
    };
    auto kstep = [&](const unsigned short* As) {
        const unsigned short* Bs = As + TMv * 64;
#pragma unroll
        for (int ks = 0; ks < 2; ++ks) {
            const int slot = ((ks * 4 + q) ^ (fr & 7)) * 8;  // de-swizzle
            bf16x8 a[IT], b[JT];
#pragma unroll
            for (int i = 0; i < IT; ++i)
                a[i] = *(const bf16x8*)(As + (wm * WMv + i * 16 + fr) * 64 + slot);
#pragma unroll
            for (int j = 0; j < JT; ++j)
                b[j] = *(const bf16x8*)(Bs + (wn * WNv + j * 16 + fr) * 64 + slot);
#pragma unroll
            for (int i = 0; i < IT; ++i)
#pragma unroll
                for (int j = 0; j < JT; ++j)
                    acc[i][j] = __builtin_amdgcn_mfma_f32_16x16x32_bf16(a[i], b[j], acc[i][j], 0, 0, 0);
        }
    };

    const int nk = K >> 6;

    // EPI==2: per-thread inv for the 2 in-loop attn rows (regs); drain BEFORE
    // staging so counted in-loop waits see only tile loads + attn stores.
    float ainv[EPI == 2 ? (TMv / 32) : 1];
    if constexpr (EPI == 2) {
        const int rsub = lane >> 3;
#pragma unroll
        for (int pass = 0; pass < TMv / 32; ++pass)
            ainv[pass] = 1.0f / (invs[m0 + w * (TMv / 4) + pass * 8 + rsub] + 1e-6f);
        vmw<0>();
    }

    stage(S, 0);
    if constexpr (NBUF == 3) { if (nk > 1) stage(S + TILE, 64); }

    for (int kt = 0; kt < nk; ++kt) {
        // prefetch the tile NBUF-1 ahead; buffer being written was last read
        // in iter kt-1 (fenced by its lgkmcnt(0)+barrier) -- race-free.
        const int pre = kt + NBUF - 1;
        if (pre < nk) stage(S + (pre % NBUF) * TILE, pre << 6);

        // wait only for tile kt's loads (oldest-first retirement, m135)
        if constexpr (EPI == 2) {
            // NBUF==2; +4 slack for the previous iteration's 4 attn stores.
            if (kt + 1 < nk) { if (kt >= 1) vmw<NPASS + 4>(); else vmw<NPASS>(); }
            else             { if (kt >= 1) vmw<4>();         else vmw<0>(); }
        } else if constexpr (NBUF == 3) {
            if (kt + 2 < nk)      vmw<2 * NPASS>();
            else if (kt + 1 < nk) vmw<NPASS>();
            else                  vmw<0>();
        } else {
            if (kt + 1 < nk) vmw<NPASS>(); else vmw<0>();
        }
        __builtin_amdgcn_s_barrier();

        kstep(S + (kt % NBUF) * TILE);

        if constexpr (EPI == 2) {
            // normalized fp32 attn write for this k-tile's A(e) rows, from LDS (every kt)
            const unsigned short* As = S + (kt & 1) * TILE;
            const int chunk = lane & 7;
            const int rsub  = lane >> 3;
#pragma unroll
            for (int pass = 0; pass < TMv / 32; ++pass) {
                const int row = w * (TMv / 4) + pass * 8 + rsub;
                const uint4 u = *(const uint4*)(As + row * 64 + ((chunk ^ (row & 7)) * 8));
                const float iv = ainv[pass];
                float4 lo, hi;
                lo.x = bf2f((unsigned short)(u.x & 0xffff)) * iv; lo.y = bf2f((unsigned short)(u.x >> 16)) * iv;
                lo.z = bf2f((unsigned short)(u.y & 0xffff)) * iv; lo.w = bf2f((unsigned short)(u.y >> 16)) * iv;
                hi.x = bf2f((unsigned short)(u.z & 0xffff)) * iv; hi.y = bf2f((unsigned short)(u.z >> 16)) * iv;
                hi.z = bf2f((unsigned short)(u.w & 0xffff)) * iv; hi.w = bf2f((unsigned short)(u.w >> 16)) * iv;
                float* op = aux + (size_t)(m0 + row) * Lsz + (kt << 6) + chunk * 8;
                *(float4*)op = lo;
                *(float4*)(op + 4) = hi;
            }
        }

        // readers done with buf[kt] before a later iter overwrites it; do NOT drain vmcnt
        asm volatile("s_waitcnt lgkmcnt(0)" ::: "memory");
        __builtin_amdgcn_s_barrier();
    }

    // ---- epilogue: acc -> LDS fp32 (padded) -> vectorized coalesced global IO ----
    {
        float* Lf = (float*)S;
        constexpr int LP = TNv + 4;
#pragma unroll
        for (int i = 0; i < IT; ++i)
#pragma unroll
            for (int j = 0; j < JT; ++j) {
                const int col = wn * WNv + j * 16 + fr;
#pragma unroll
                for (int r = 0; r < 4; ++r) {
                    const int row = wm * WMv + i * 16 + q * 4 + r;
                    Lf[row * LP + col] = acc[i][j][r] * alpha;
                }
            }
        __syncthreads();

        constexpr int SEGS = TNv / 32;     // 32-col segments per row
        constexpr int RPI  = 256 / SEGS;   // rows covered per pass
#pragma unroll
        for (int it2 = 0; it2 < TMv / RPI; ++it2) {
            const int row = it2 * RPI + t / SEGS;
            const int c0  = (t % SEGS) * 32;
            const float* src = Lf + row * LP + c0;

            if constexpr (EPI == 0 && sizeof(OutT) == 4) {
                float* dst = (float*)C + (size_t)(m0 + row) * ldc + n0 + c0;
#pragma unroll
                for (int v4 = 0; v4 < 8; ++v4)
                    *(f32x4*)(dst + v4 * 4) = *(const f32x4*)(src + v4 * 4);
            } else if constexpr (EPI == 0) {
                unsigned short* dst = (unsigned short*)C + (size_t)(m0 + row) * ldc + n0 + c0;
#pragma unroll
                for (int v8 = 0; v8 < 4; ++v8) {
                    bf16x8 o;
#pragma unroll
                    for (int e = 0; e < 8; ++e) o[e] = (short)f2bf(src[v8 * 8 + e]);
                    *(bf16x8*)(dst + v8 * 8) = o;
                }
            } else if constexpr (EPI == 1) {
                unsigned short* dst = (unsigned short*)C + (size_t)(m0 + row) * ldc + n0 + c0;
                const unsigned char* mrow = maskb + (size_t)(m0 + row) * Lsz + n0 + c0;
                unsigned char mloc[32];
                *(uint4*)mloc        = *(const uint4*)mrow;
                *(uint4*)(mloc + 16) = *(const uint4*)(mrow + 16);
                float rsum = 0.f;
#pragma unroll
                for (int v8 = 0; v8 < 4; ++v8) {
                    bf16x8 o;
#pragma unroll
                    for (int e = 0; e < 8; ++e) {
                        const float m = (float)mloc[v8 * 8 + e];
                        float vv = fminf(fmaxf(src[v8 * 8 + e], -15.f), 15.f) * m;
                        vv = __expf(vv) * m;
                        const unsigned short us = f2bf(vv);
                        o[e] = (short)us;
                        rsum += bf2f(us);   // sum the ROUNDED value
                    }
                    *(bf16x8*)(dst + v8 * 8) = o;
                }
                // combine the 4 segs of this row (threads t, t^1, t^2 share the row)
                rsum += __shfl_xor(rsum, 1, 64);
                rsum += __shfl_xor(rsum, 2, 64);
                if ((t & 3) == 0) atomicAdd(&aux[m0 + row], rsum);
            } else { // EPI == 2: attnv = acc * inv[row]
                unsigned short* dst = (unsigned short*)C + (size_t)(m0 + row) * ldc + n0 + c0;
                const float iv = 1.0f / (invs[m0 + row] + 1e-6f);
#pragma unroll
                for (int v8 = 0; v8 < 4; ++v8) {
                    bf16x8 o;
#pragma unroll
                    for (int e = 0; e < 8; ++e) o[e] = (short)f2bf(src[v8 * 8 + e] * iv);
                    *(bf16x8*)(dst + v8 * 8) = o;
                }
            }
        }
    }
}

// ---- fp32->bf16 cast of all GEMM inputs + int32 mask -> BYTE {0,1} + rowsum zero ----
__global__ __launch_bounds__(256) void cast_all(
    const float* __restrict__ q, const float* __restrict__ k, const float* __restrict__ v,
    const float* __restrict__ wq, const float* __restrict__ wk, const float* __restrict__ wv,
    const float* __restrict__ fw, const int* __restrict__ mask,
    unsigned short* __restrict__ qb, unsigned short* __restrict__ kb, unsigned short* __restrict__ vb,
    unsigned short* __restrict__ wqb, unsigned short* __restrict__ wkb, unsigned short* __restrict__ wvb,
    unsigned short* __restrict__ fwb, unsigned char* __restrict__ mb,
    float* __restrict__ rs)
{
    const int gid = blockIdx.x * 256 + threadIdx.x;
    const int NQ = 262144;   // 1048576/4
    const int NW = 131072;   // 524288/4
    const int NF = 3 * NQ + 4 * NW;   // 1310720 float4 groups
    const int NM = 1048576;           // mask int4 groups
    if (gid >= NF) {
        const int off = gid - NF;
        if (off >= NM) {
            const int ri = off - NM;
            if (ri < 8192) ((float4*)rs)[ri] = (float4){0.f, 0.f, 0.f, 0.f};
            return;
        }
        const int4 mi = ((const int4*)mask)[off];
        uchar4 o;
        o.x = mi.x ? 1 : 0;
        o.y = mi.y ? 1 : 0;
        o.z = mi.z ? 1 : 0;
        o.w = mi.w ? 1 : 0;
        ((uchar4*)mb)[off] = o;
        return;
    }
    const float* src; unsigned short* dst; int off;
    if      (gid < NQ)            { src = q;  dst = qb;  off = gid; }
    else if (gid < 2 * NQ)        { src = k;  dst = kb;  off = gid - NQ; }
    else if (gid < 3 * NQ)        { src = v;  dst = vb;  off = gid - 2 * NQ; }
    else if (gid < 3 * NQ + NW)   { src = wq; dst = wqb; off = gid - 3 * NQ; }
    else if (gid < 3 * NQ + 2*NW) { src = wk; dst = wkb; off = gid - 3 * NQ - NW; }
    else if (gid < 3 * NQ + 3*NW) { src = wv; dst = wvb; off = gid - 3 * NQ - 2 * NW; }
    else                          { src = fw; dst = fwb; off = gid - 3 * NQ - 3 * NW; }
    float4 f = ((const float4*)src)[off];
    ushort4 o;
    o.x = f2bf(f.x); o.y = f2bf(f.y); o.z = f2bf(f.z); o.w = f2bf(f.w);
    ((ushort4*)dst)[off] = o;
}

// ---- sum 4 fc split-K partials + fc_b + residual -> LayerNorm -> out ----
__global__ __launch_bounds__(256) void ln_kernel(const float* __restrict__ gout,
                                                 const float* __restrict__ qin,
                                                 const float* __restrict__ fc_b,
                                                 const float* __restrict__ ln_g,
                                                 const float* __restrict__ ln_b,
                                                 float* __restrict__ out)
{
    const int row = blockIdx.x;
    const int t = threadIdx.x;
    const size_t idx = (size_t)row * Dsz + t;
    const size_t P = (size_t)NROWS * Dsz;
    const float val = gout[idx] + gout[idx + P] + gout[idx + 2 * P] + gout[idx + 3 * P]
                    + fc_b[t] + qin[idx];

    __shared__ float red[4];
    float s = val;
#pragma unroll
    for (int o = 32; o > 0; o >>= 1) s += __shfl_down(s, o, 64);
    const int lane = t & 63, w = t >> 6;
    if (lane == 0) red[w] = s;
    __syncthreads();
    const float mu = (red[0] + red[1] + red[2] + red[3]) * (1.0f / Dsz);
    __syncthreads();

    float d = val - mu;
    float s2 = d * d;
#pragma unroll
    for (int o = 32; o > 0; o >>= 1) s2 += __shfl_down(s2, o, 64);
    if (lane == 0) red[w] = s2;
    __syncthreads();
    const float var = (red[0] + red[1] + red[2] + red[3]) * (1.0f / Dsz);

    out[idx] = d * rsqrtf(var + 1e-5f) * ln_g[t] + ln_b[t];
}

extern "C" void kernel_launch(void* const* d_in, const int* in_sizes, int n_in,
                              void* d_out, int out_size, void* d_ws, size_t ws_size,
                              hipStream_t stream)
{
    const float* q    = (const float*)d_in[0];
    const int*   mask = (const int*)d_in[1];
    const float* k    = (const float*)d_in[2];
    const float* v    = (const float*)d_in[3];
    const float* w_qs = (const float*)d_in[4];
    const float* w_ks = (const float*)d_in[5];
    const float* w_vs = (const float*)d_in[6];
    const float* fc_w = (const float*)d_in[7];
    const float* fc_b = (const float*)d_in[8];
    const float* ln_g = (const float*)d_in[9];
    const float* ln_b = (const float*)d_in[10];

    float* out  = (float*)d_out;                       // [B,L,D]
    float* attn = (float*)d_out + (size_t)NROWS * Dsz; // [H*B,L,L] fp32 normalized

    // Workspace layout (ushort units)
    unsigned short* wsu = (unsigned short*)d_ws;
    unsigned short* qh     = wsu;                                  // [4096,2048]
    unsigned short* kh     = qh + (size_t)NROWS * HD;              // [4096,2048]
    unsigned short* q_bf   = kh + (size_t)NROWS * HD;              // [4096,256] x3
    unsigned short* k_bf   = q_bf + (size_t)NROWS * Dsz;
    unsigned short* v_bf   = k_bf + (size_t)NROWS * Dsz;
    unsigned short* wq_bf  = v_bf + (size_t)NROWS * Dsz;           // [2048,256] x3
    unsigned short* wk_bf  = wq_bf + (size_t)HD * Dsz;
    unsigned short* wv_bf  = wk_bf + (size_t)HD * Dsz;
    unsigned short* vt     = wv_bf + (size_t)HD * Dsz;             // [B,2048,1024]
    unsigned short* attn_e = vt + (size_t)Bsz * HD * Lsz;          // [32,1024,1024] unnormalized e
    unsigned short* attnv  = attn_e + (size_t)32 * Lsz * Lsz;      // [4096,2048]
    unsigned short* fcw_bf = attnv + (size_t)NROWS * HD;           // [256,2048]
    float*          rowsum = (float*)(fcw_bf + (size_t)Dsz * HD);  // [32768] atomic row sums
    float*          fcout  = rowsum + 32768;                       // [4,4096,256] split-K partials
    unsigned char*  maskb  = (unsigned char*)(fcout + (size_t)4 * NROWS * Dsz); // [B,L,L] bytes {0,1}

    dim3 blk(256);

    // 0) cast everything to bf16 (mask -> bytes) + zero rowsum
    cast_all<<<dim3(9248), blk, 0, stream>>>(q, k, v, w_qs, w_ks, w_vs, fc_w, mask,
                                             q_bf, k_bf, v_bf, wq_bf, wk_bf, wv_bf, fcw_bf, maskb,
                                             rowsum);

    // 1) FUSED: q/k projections (z=0,1) + vt[b] (z=2..5). 64x128 BK=64, depth-2
    //    prefetch (NBUF=3, 72 KB, 2 wg/CU), grid 64x16x6, XCD-swizzled.
    {
        dim3 grid(NROWS / 64, HD / 128, 6);
        gemm_bt<64, 128, unsigned short, 0, 2, true, 3, 64, 16, 6><<<grid, blk, 0, stream>>>(
            q_bf, wq_bf, qh,
            Dsz, Dsz, Dsz, HD, 2,
            0, (long long)NROWS * Dsz, 0, (long long)HD * Dsz, 0, (long long)NROWS * HD,
            1.0f, nullptr, 0, nullptr, 0, 0, nullptr,
            wv_bf, v_bf, vt);
    }

    // 2) scores + clamp/mask/exp + row-sum atomics (vectorized epilogue).
    //    64x128 BK=64, NBUF=3, grid 16x8x32, XCD-swizzled.
    {
        dim3 grid(Lsz / 64, Lsz / 128, Hsz * Bsz);
        gemm_bt<64, 128, unsigned short, 1, 2, false, 3, 16, 8, 32><<<grid, blk, 0, stream>>>(
            qh, kh, attn_e,
            Dsz, HD, HD, Lsz, Bsz,
            Dsz, (long long)Lsz * HD, Dsz, (long long)Lsz * HD,
            (long long)Bsz * Lsz * Lsz, (long long)Lsz * Lsz,
            INV_TEMP, maskb, (long long)Lsz * Lsz, nullptr, 0, 0, rowsum,
            nullptr, nullptr, nullptr);
    }

    // 3) pv: attnv = (e @ vt^T) * inv[row]; fp32 attn written IN-LOOP from LDS.
    //    64x256 (full-D), BK=64, NBUF=2, K=1024 (nk=16: pipeline fills),
    //    grid 16x1x32, XCD-swizzled.
    {
        dim3 grid(Lsz / 64, 1, Hsz * Bsz);
        gemm_bt<64, 256, unsigned short, 2, 2, false, 2, 16, 1, 32><<<grid, blk, 0, stream>>>(
            attn_e, vt, attnv,
            Lsz, Lsz, Lsz, HD, Bsz,
            (long long)Bsz * Lsz * Lsz, (long long)Lsz * Lsz,
            (long long)Dsz * Lsz, (long long)HD * Lsz,
            Dsz, (long long)Lsz * HD,
            1.0f, nullptr, 0, rowsum, (long long)Bsz * Lsz, (long long)Lsz, attn,
            nullptr, nullptr, nullptr);
    }

    // 4) fc split-K x4: fcout[p] = attnv[:, p*512:+512] @ fc_w[:, p*512:+512]^T.
    //    64x128 BK=64, NBUF=3 (nk=8), grid 64x2x4, XCD-swizzled.
    {
        dim3 grid(NROWS / 64, Dsz / 128, 4);
        gemm_bt<64, 128, float, 0, 2, false, 3, 64, 2, 4><<<grid, blk, 0, stream>>>(
            attnv, fcw_bf, fcout,
            512, HD, HD, Dsz, 4,
            0, 512, 0, 512, 0, (long long)NROWS * Dsz,
            1.0f, nullptr, 0, nullptr, 0, 0, nullptr,
            nullptr, nullptr, nullptr);
    }

    // 5) sum partials + bias + residual + LayerNorm
    ln_kernel<<<dim3(NROWS), blk, 0, stream>>>(fcout, q, fc_b, ln_g, ln_b, out);
}